// Round 2
// baseline (226.537 us; speedup 1.0000x reference)
//
#include <hip/hip_runtime.h>
#include <cstdint>

// NNLS PGD step (all tensors FLOAT32, k int32):
//   new_X = relu(th1 @ Y + weight); Y_new = new_X + (k-1)/(k+2)*(new_X - X_old)
// out (f32) = [Y_new (KB) | new_X (KB) | k+1 (1) | weight (KB)].
//
// R2: two-kernel scheme.
//  K1 (nnls_conv): th1 -> bf16 K-tiled A [kt][m][32]; Y -> bf16 K-tiled
//    TRANSPOSED Yt [kt][n][32] (LDS-tile transpose). ~54 MB traffic.
//  K2 (nnls_gemm2): 128x64 tile, 4 waves, BK=32, double-buffered LDS filled
//    by global_load_lds dwordx4 (no VALU converts, no reg staging, 1KB
//    contiguous per instr), 6 ds_read_b128 + 8 MFMA per wave per K-step,
//    one barrier per K-step. Linear [row][64B] LDS rows alternate bank
//    halves -> b128 frag reads are even across granules (floor, no conflict).
//  Fallback single-kernel path if ws_size < 18 MiB.

#define KDIM 1024
#define NDIM 8192
#define KB_ELEMS (1024UL * 8192UL)
#define YT_BYTES (8192UL * 1024UL * 2UL) /* 16 MiB */
#define AB_BYTES (1024UL * 1024UL * 2UL) /*  2 MiB */
#define WS_NEED (YT_BYTES + AB_BYTES)

typedef short short8 __attribute__((ext_vector_type(8)));
typedef float f32x4 __attribute__((ext_vector_type(4)));

struct __attribute__((aligned(4))) f4u { float x, y, z, w; };  // 4B-aligned 16B store

__device__ __forceinline__ uint32_t pk2(float a, float b) {
  uint32_t ua = __builtin_bit_cast(uint32_t, a) + 0x8000u;
  uint32_t ub = __builtin_bit_cast(uint32_t, b) + 0x8000u;
  return (ua >> 16) | (ub & 0xFFFF0000u);
}

__device__ __forceinline__ void ldsload16(const void* g, void* l) {
  __builtin_amdgcn_global_load_lds(
      (const __attribute__((address_space(1))) uint32_t*)g,
      (__attribute__((address_space(3))) uint32_t*)l, 16, 0, 0);
}

// ---------------- K1: convert/transpose into workspace ----------------
// blocks 0..1023: Y[32k x 256n] tile -> Yt[kt][n][32] bf16
// blocks 1024..1151: th1 -> A[kt][m][32] bf16 (one (m,kt) pair per thread)
__global__ __launch_bounds__(256) void nnls_conv(
    const float* __restrict__ th1, const float* __restrict__ Y,
    char* __restrict__ ws)
{
  unsigned short* yt  = (unsigned short*)ws;
  unsigned short* abf = (unsigned short*)(ws + YT_BYTES);
  const int tid = threadIdx.x;
  if (blockIdx.x < 1024) {
    const int kt = blockIdx.x >> 5;   // 0..31
    const int nb = blockIdx.x & 31;   // 0..31
    const int k0 = kt * 32, n0 = nb * 256;
    __shared__ float t[32][260];      // pad 260: conflict-free both phases
#pragma unroll
    for (int it = 0; it < 8; ++it) {
      const int r = it * 4 + (tid >> 6);
      const float4 v = *(const float4*)&Y[(size_t)(k0 + r) * NDIM + n0 + (tid & 63) * 4];
      *(float4*)&t[r][(tid & 63) * 4] = v;
    }
    __syncthreads();
    const int n = tid;                // 0..255 (column of the tile)
    __attribute__((aligned(16))) uint32_t o[16];
#pragma unroll
    for (int r2 = 0; r2 < 16; ++r2) o[r2] = pk2(t[2 * r2][n], t[2 * r2 + 1][n]);
    uint32_t* dst = (uint32_t*)&yt[((size_t)kt * NDIM + (n0 + n)) * 32];
#pragma unroll
    for (int q = 0; q < 4; ++q) *(uint4*)&dst[q * 4] = *(uint4*)&o[q * 4];
  } else {
    const int id = (blockIdx.x - 1024) * 256 + tid;  // 0..32767 = 1024m x 32kt
    const int m = id >> 5, kt = id & 31;
    const float4* s4 = (const float4*)(th1 + (size_t)m * KDIM + kt * 32);
    __attribute__((aligned(16))) uint32_t o[16];
#pragma unroll
    for (int q = 0; q < 8; ++q) {
      const float4 v = s4[q];
      o[2 * q]     = pk2(v.x, v.y);
      o[2 * q + 1] = pk2(v.z, v.w);
    }
    uint32_t* dst = (uint32_t*)&abf[((size_t)kt * KDIM + m) * 32];
#pragma unroll
    for (int q = 0; q < 4; ++q) *(uint4*)&dst[q * 4] = *(uint4*)&o[q * 4];
  }
}

// ---------------- K2: GEMM + fused epilogue ----------------
// 128x64 tile, 256 thr = 4 waves (2m x 2n), wave tile 64x32 (4x2 MFMA).
// grid (8192/64, 1024/128) = 1024 blocks -> 4 blocks/CU, 16 waves/CU.
__global__ __launch_bounds__(256, 4) void nnls_gemm2(
    const char* __restrict__ ws, const float* __restrict__ xold,
    const int* __restrict__ kin, const float* __restrict__ weight,
    float* __restrict__ out)
{
  const char* yt = ws;
  const char* ab = ws + YT_BYTES;
  __shared__ __align__(16) char smem[24576];
  // buf p: As @ p*12288 (8KB: [128][32]bf16), Bs @ p*12288+8192 (4KB: [64][32])

  const int tid  = threadIdx.x;
  const int lane = tid & 63;
  const int w    = tid >> 6;            // 0..3
  const int wm = w >> 1, wn = w & 1;    // 2 x 2 wave grid
  const int quad = lane >> 4, nl = lane & 15;

  const int m0 = blockIdx.y * 128;
  const int n0 = blockIdx.x * 64;

  // staging sources: per-lane = uniform_base + lane*16 (contiguous 1KB/instr)
  const char* ag = ab + (size_t)m0 * 64 + w * 2048 + lane * 16;  // A rows w*32..+31
  const char* bg = yt + (size_t)n0 * 64 + w * 1024 + lane * 16;  // B rows w*16..+15

  f32x4 acc[4][2] = {};

  {  // prologue: stage kt=0 into buf0
    char* buf = smem;
    ldsload16(ag,        buf + w * 2048);
    ldsload16(ag + 1024, buf + w * 2048 + 1024);
    ldsload16(bg,        buf + 8192 + w * 1024);
  }
  __syncthreads();

#pragma unroll 2
  for (int kt = 0; kt < 32; ++kt) {
    char* cur = smem + (kt & 1) * 12288;
    char* nxt = smem + ((kt & 1) ^ 1) * 12288;
    if (kt < 31) {  // issue next-tile DMA; drained by this iter's barrier
      const char* a2 = ag + (size_t)(kt + 1) * 65536;   // A kt-tile = 1024*64B
      const char* b2 = bg + (size_t)(kt + 1) * 524288;  // Y kt-tile = 8192*64B
      ldsload16(a2,        nxt + w * 2048);
      ldsload16(a2 + 1024, nxt + w * 2048 + 1024);
      ldsload16(b2,        nxt + 8192 + w * 1024);
    }
    const unsigned short* Asp = (const unsigned short*)cur;
    const unsigned short* Bsp = (const unsigned short*)(cur + 8192);
    short8 af[4], bf[2];
#pragma unroll
    for (int i = 0; i < 4; ++i)
      af[i] = *(const short8*)&Asp[(wm * 64 + i * 16 + nl) * 32 + quad * 8];
#pragma unroll
    for (int j = 0; j < 2; ++j)
      bf[j] = *(const short8*)&Bsp[(wn * 32 + j * 16 + nl) * 32 + quad * 8];
#pragma unroll
    for (int i = 0; i < 4; ++i)
#pragma unroll
      for (int j = 0; j < 2; ++j)
        acc[i][j] = __builtin_amdgcn_mfma_f32_16x16x32_bf16(af[i], bf[j], acc[i][j], 0, 0, 0);
    __syncthreads();  // one barrier per K-step; drains vmcnt -> nxt ready
  }

  // ---- epilogue: wave-private LDS transpose -> contiguous float4 I/O ----
  const float kf  = (float)kin[0];
  const float mom = (kf - 1.0f) / (kf + 2.0f);
  float* ep = (float*)(smem + w * 2304);  // 16 rows x 36 f32 per wave
  const int rl = lane >> 3;               // read row-in-group 0..7
  const int cq = lane & 7;                // read col quarter (x4 floats)

#pragma unroll
  for (int i = 0; i < 4; ++i) {
    // scatter acc chunk i (16 rows x 32 cols); stride 36: 2-way writes (free)
#pragma unroll
    for (int j = 0; j < 2; ++j)
#pragma unroll
      for (int r = 0; r < 4; ++r)
        ep[(quad * 4 + r) * 36 + (j * 16 + nl)] = acc[i][j][r];
    // no barrier: ep wave-private; same-wave DS ops are in-order

    const int mgb = m0 + wm * 64 + i * 16;
#pragma unroll
    for (int t = 0; t < 2; ++t) {
      const int row = t * 8 + rl;
      const float4 cv = *(const float4*)&ep[row * 36 + cq * 4];  // even granules
      const int ng = n0 + wn * 32 + cq * 4;
      const size_t idx = (size_t)(mgb + row) * NDIM + ng;  // 8 rows x 128B runs
      const float4 wv = *(const float4*)&weight[idx];
      const float4 xo = *(const float4*)&xold[idx];
      float4 nx, yn;
      nx.x = fmaxf(cv.x + wv.x, 0.0f); nx.y = fmaxf(cv.y + wv.y, 0.0f);
      nx.z = fmaxf(cv.z + wv.z, 0.0f); nx.w = fmaxf(cv.w + wv.w, 0.0f);
      yn.x = nx.x + mom * (nx.x - xo.x); yn.y = nx.y + mom * (nx.y - xo.y);
      yn.z = nx.z + mom * (nx.z - xo.z); yn.w = nx.w + mom * (nx.w - xo.w);
      *(float4*)&out[idx] = yn;               // Y_new (16B aligned)
      *(float4*)&out[KB_ELEMS + idx] = nx;    // new_X (16B aligned)
      f4u s; s.x = wv.x; s.y = wv.y; s.z = wv.z; s.w = wv.w;
      *(f4u*)&out[2 * KB_ELEMS + 1 + idx] = s;  // weight passthrough (4B aligned)
    }
  }

  if (blockIdx.x == 0 && blockIdx.y == 0 && tid == 0)
    out[2 * KB_ELEMS] = (float)(kin[0] + 1);
}

// ---------------- fallback: R1 single-kernel path (ws too small) ----------------
#define LDA 40
__global__ __launch_bounds__(512, 4) void nnls_gemm_v1(
    const float* __restrict__ th1, const float* __restrict__ Y,
    const float* __restrict__ xold, const int* __restrict__ kin,
    const float* __restrict__ weight, float* __restrict__ out)
{
  __shared__ __align__(16) char smem[40960];
  unsigned short* As0 = (unsigned short*)smem;
  unsigned short* Bs0 = (unsigned short*)(smem + 10240);
  unsigned short* As1 = (unsigned short*)(smem + 20480);
  unsigned short* Bs1 = (unsigned short*)(smem + 30720);

  const int tid  = threadIdx.x;
  const int lane = tid & 63;
  const int w    = tid >> 6;
  const int wm = w >> 1, wn = w & 1;
  const int quad = lane >> 4, nl = lane & 15;
  const int m0 = blockIdx.y * 128;
  const int n0 = blockIdx.x * 128;
  const int ar = tid >> 3;
  const int ac = tid & 7;
  const float* abase = th1 + (size_t)(m0 + ar) * KDIM + ac * 4;
  const int bn = tid & 127;
  const int bk = (tid >> 7) * 8;
  const float* ybase = Y + (size_t)bk * NDIM + n0 + bn;

  float4 abv[2];
  float  yb[8];
  abv[0] = *(const float4*)(abase);
  abv[1] = *(const float4*)(abase + (size_t)64 * KDIM);
#pragma unroll
  for (int r = 0; r < 8; ++r) yb[r] = ybase[(size_t)r * NDIM];

  f32x4 acc[2][4] = {};

#pragma unroll 2
  for (int kt = 0; kt < 32; ++kt) {
    unsigned short* Asp = (kt & 1) ? As1 : As0;
    unsigned short* Bsp = (kt & 1) ? Bs1 : Bs0;
    {
      uint2 d0; d0.x = pk2(abv[0].x, abv[0].y); d0.y = pk2(abv[0].z, abv[0].w);
      *(uint2*)&Asp[ar * LDA + ac * 4] = d0;
      uint2 d1; d1.x = pk2(abv[1].x, abv[1].y); d1.y = pk2(abv[1].z, abv[1].w);
      *(uint2*)&Asp[(ar + 64) * LDA + ac * 4] = d1;
      uint4 e;
      e.x = pk2(yb[0], yb[1]); e.y = pk2(yb[2], yb[3]);
      e.z = pk2(yb[4], yb[5]); e.w = pk2(yb[6], yb[7]);
      *(uint4*)&Bsp[bn * LDA + bk] = e;
    }
    __syncthreads();
    if (kt < 31) {
      const float* an = abase + (kt + 1) * 32;
      abv[0] = *(const float4*)(an);
      abv[1] = *(const float4*)(an + (size_t)64 * KDIM);
      const float* yn = ybase + (size_t)((kt + 1) * 32) * NDIM;
#pragma unroll
      for (int r = 0; r < 8; ++r) yb[r] = yn[(size_t)r * NDIM];
    }
    short8 af[2], bf[4];
#pragma unroll
    for (int i = 0; i < 2; ++i)
      af[i] = *(const short8*)&Asp[(wm * 32 + i * 16 + nl) * LDA + quad * 8];
#pragma unroll
    for (int j = 0; j < 4; ++j)
      bf[j] = *(const short8*)&Bsp[(wn * 64 + j * 16 + nl) * LDA + quad * 8];
#pragma unroll
    for (int i = 0; i < 2; ++i)
#pragma unroll
      for (int j = 0; j < 4; ++j)
        acc[i][j] = __builtin_amdgcn_mfma_f32_16x16x32_bf16(af[i], bf[j], acc[i][j], 0, 0, 0);
    __syncthreads();
  }
  __syncthreads();

  const float kf  = (float)kin[0];
  const float mom = (kf - 1.0f) / (kf + 2.0f);
  float* ep = (float*)smem + w * 1088;
  const int u  = lane >> 4;
  const int mc = lane & 15;
#pragma unroll
  for (int i = 0; i < 2; ++i) {
#pragma unroll
    for (int j = 0; j < 4; ++j)
#pragma unroll
      for (int r = 0; r < 4; ++r)
        ep[(quad * 4 + r) * 68 + (j * 16 + nl)] = acc[i][j][r];
    const int mgb = m0 + wm * 32 + i * 16;
#pragma unroll
    for (int t = 0; t < 4; ++t) {
      const int row = t * 4 + u;
      const float4 cv = *(const float4*)&ep[row * 68 + mc * 4];
      const int ng = n0 + wn * 64 + mc * 4;
      const size_t idx = (size_t)(mgb + row) * NDIM + ng;
      const float4 wv = *(const float4*)&weight[idx];
      const float4 xo = *(const float4*)&xold[idx];
      float4 nx, yn;
      nx.x = fmaxf(cv.x + wv.x, 0.0f); nx.y = fmaxf(cv.y + wv.y, 0.0f);
      nx.z = fmaxf(cv.z + wv.z, 0.0f); nx.w = fmaxf(cv.w + wv.w, 0.0f);
      yn.x = nx.x + mom * (nx.x - xo.x); yn.y = nx.y + mom * (nx.y - xo.y);
      yn.z = nx.z + mom * (nx.z - xo.z); yn.w = nx.w + mom * (nx.w - xo.w);
      *(float4*)&out[idx] = yn;
      *(float4*)&out[KB_ELEMS + idx] = nx;
      f4u s; s.x = wv.x; s.y = wv.y; s.z = wv.z; s.w = wv.w;
      *(f4u*)&out[2 * KB_ELEMS + 1 + idx] = s;
    }
  }
  if (blockIdx.x == 0 && blockIdx.y == 0 && tid == 0)
    out[2 * KB_ELEMS] = (float)(kin[0] + 1);
}

extern "C" void kernel_launch(void* const* d_in, const int* in_sizes, int n_in,
                              void* d_out, int out_size, void* d_ws, size_t ws_size,
                              hipStream_t stream) {
  const float* th1  = (const float*)d_in[0];
  const float* Y    = (const float*)d_in[1];
  const float* xold = (const float*)d_in[2];
  const int*   kin  = (const int*)d_in[3];
  const float* wgt  = (const float*)d_in[4];
  float* out = (float*)d_out;

  if (d_ws != nullptr && ws_size >= WS_NEED) {
    nnls_conv<<<1152, 256, 0, stream>>>(th1, Y, (char*)d_ws);
    nnls_gemm2<<<dim3(NDIM / 64, KDIM / 128), 256, 0, stream>>>(
        (const char*)d_ws, xold, kin, wgt, out);
  } else {
    nnls_gemm_v1<<<dim3(NDIM / 128, KDIM / 128), 512, 0, stream>>>(
        th1, Y, xold, kin, wgt, out);
  }
}